// Round 1
// baseline (329.414 us; speedup 1.0000x reference)
//
#include <hip/hip_runtime.h>
#include <math.h>

#define DH 128
#define BCAP 16384  // slots per 512-node bucket (mean ~8163, >20 sigma headroom)

typedef __bf16 bf8_t __attribute__((ext_vector_type(8)));
typedef short short8 __attribute__((ext_vector_type(8)));
typedef float f4_t __attribute__((ext_vector_type(4)));
typedef float f2_t __attribute__((ext_vector_type(2)));

__device__ inline unsigned short f2b(float f) {
    unsigned int u = __builtin_bit_cast(unsigned int, f);
    u = u + 0x7fffu + ((u >> 16) & 1u);  // RNE
    return (unsigned short)(u >> 16);
}
__device__ inline float b2f(unsigned short h) {
    return __builtin_bit_cast(float, (unsigned int)h << 16);
}

// ---------- Pass A: bucket edges by dst>>9 ----------
__global__ __launch_bounds__(256) void k_bucket(const int* __restrict__ row,
                                                const int* __restrict__ col,
                                                int E, int nbuck, int chunk,
                                                unsigned int* __restrict__ pairs,
                                                int* __restrict__ bcur) {
    __shared__ int lcnt[256];
    __shared__ int lbase[256];
    __shared__ unsigned int srec[8192];
    int t = threadIdx.x;
    int e0 = blockIdx.x * chunk;
    int e1 = min(e0 + chunk, E);
    lcnt[t] = 0;
    __syncthreads();
    for (int i = e0 + t; i < e1; i += 256) {
        int d = col[i];
        int b = d >> 9;
        int slot = atomicAdd(&lcnt[b], 1);
        srec[i - e0] = ((unsigned int)b << 22) | ((unsigned int)(d & 511) << 13)
                     | (unsigned int)slot;
    }
    __syncthreads();
    if (t < nbuck) {
        int c = lcnt[t];
        lbase[t] = (c > 0) ? atomicAdd(&bcur[t * 16], c) : 0;  // stride 16: 1 line/counter
    }
    __syncthreads();
    for (int i = e0 + t; i < e1; i += 256) {
        unsigned int r = srec[i - e0];
        int b = r >> 22;
        unsigned int dl = (r >> 13) & 511u;
        int slot = (int)(r & 8191u);
        int g = lbase[b] + slot;
        if (g < BCAP)
            pairs[(size_t)b * BCAP + g] = ((unsigned int)row[i] << 9) | dl;
    }
}

// ---------- Pass B: one block per bucket builds off/dinv/csr (LDS-local) ----------
__global__ __launch_bounds__(256) void k_build(const unsigned int* __restrict__ pairs,
                                               const int* __restrict__ bcur,
                                               int nbuck, int N,
                                               int* __restrict__ off,
                                               float* __restrict__ dinv,
                                               int* __restrict__ csr) {
    __shared__ int sb[256];
    __shared__ int cnt2[512];
    __shared__ int excl[512];
    __shared__ int curi[512];
    __shared__ int stmp[256];
    int b = blockIdx.x, t = threadIdx.x;
    sb[t] = (t < nbuck) ? min(bcur[t * 16], BCAP) : 0;
    __syncthreads();
    for (int d = 1; d < 256; d <<= 1) {
        int v = (t >= d) ? sb[t - d] : 0;
        __syncthreads();
        sb[t] += v;
        __syncthreads();
    }
    int base = (b == 0) ? 0 : sb[b - 1];
    int cnt = sb[b] - base;
    int node0 = b << 9;
    int nodes = min(512, N - node0);
    cnt2[t] = 0; cnt2[t + 256] = 0;
    __syncthreads();
    const unsigned int* pp = pairs + (size_t)b * BCAP;
    for (int i = t; i < cnt; i += 256)
        atomicAdd(&cnt2[pp[i] & 511u], 1);
    __syncthreads();
    stmp[t] = cnt2[2 * t] + cnt2[2 * t + 1];
    __syncthreads();
    for (int d = 1; d < 256; d <<= 1) {
        int v = (t >= d) ? stmp[t - d] : 0;
        __syncthreads();
        stmp[t] += v;
        __syncthreads();
    }
    int pre = (t == 0) ? 0 : stmp[t - 1];
    excl[2 * t] = pre;
    excl[2 * t + 1] = pre + cnt2[2 * t];
    __syncthreads();
    if (t < nodes) {
        off[node0 + t] = base + excl[t];
        dinv[node0 + t] = rsqrtf((float)(cnt2[t] + 1));
    }
    int t2 = t + 256;
    if (t2 < nodes) {
        off[node0 + t2] = base + excl[t2];
        dinv[node0 + t2] = rsqrtf((float)(cnt2[t2] + 1));
    }
    if (t == 0) off[node0 + nodes] = base + cnt;
    curi[t] = excl[t]; curi[t + 256] = excl[t + 256];
    __syncthreads();
    for (int i = t; i < cnt; i += 256) {
        unsigned int p = pp[i];
        int d = (int)(p & 511u);
        int slot = atomicAdd(&curi[d], 1);
        csr[base + slot] = (int)(p >> 9);
    }
}

// ---------- W prep (both layers): Wt[n][k] = bf16(W[k][n]) ----------
__global__ void k_prepW(const float* __restrict__ W1, const float* __restrict__ W2,
                        unsigned short* __restrict__ Wt1, unsigned short* __restrict__ Wt2) {
    int t = blockIdx.x * blockDim.x + threadIdx.x;  // 32768
    const float* W = (t < 16384) ? W1 : W2;
    unsigned short* Wt = (t < 16384) ? Wt1 : Wt2;
    int v = t & 16383;
    int k = v >> 7, n = v & 127;
    Wt[n * DH + k] = f2b(W[k * DH + n]);
}

// ---------- MFMA GEMM -> fp8 e4m3 table, lane-major permuted rows ----------
// Row r byte p = l16*8 + j holds col j*16+l16 of (X[r]@W)*dinv[r].
// Un-permute at aggregation store: col of byte p = (p&7)*16 + (p>>3).
__global__ __launch_bounds__(256) void k_gemm_mfma(const void* __restrict__ Xin, int x_is_bf16,
                                                   const unsigned short* __restrict__ Wt,
                                                   const float* __restrict__ dinv,
                                                   unsigned char* __restrict__ Y, int nrows) {
    __shared__ unsigned short Xs[64 * 136];
    __shared__ unsigned short Ws[128 * 136];
    int t = threadIdx.x;
    int row0 = blockIdx.x * 64;

    for (int v = t; v < 128 * 32; v += 256) {
        int n = v >> 5, kq = v & 31;
        ushort4 w = ((const ushort4*)Wt)[v];
        *(ushort4*)&Ws[n * 136 + kq * 4] = w;
    }
    if (x_is_bf16) {
        const unsigned short* X = (const unsigned short*)Xin;
        for (int v = t; v < 64 * 32; v += 256) {
            int r = v >> 5, cq = v & 31;
            int gr = row0 + r;
            ushort4 h;
            if (gr < nrows) h = ((const ushort4*)X)[(size_t)gr * 32 + cq];
            else { h.x = 0; h.y = 0; h.z = 0; h.w = 0; }
            *(ushort4*)&Xs[r * 136 + cq * 4] = h;
        }
    } else {
        const float* X = (const float*)Xin;
        for (int v = t; v < 64 * 32; v += 256) {
            int r = v >> 5, cq = v & 31;
            int gr = row0 + r;
            ushort4 h;
            if (gr < nrows) {
                float4 xv = ((const float4*)X)[(size_t)gr * 32 + cq];
                h.x = f2b(xv.x); h.y = f2b(xv.y); h.z = f2b(xv.z); h.w = f2b(xv.w);
            } else { h.x = 0; h.y = 0; h.z = 0; h.w = 0; }
            *(ushort4*)&Xs[r * 136 + cq * 4] = h;
        }
    }
    __syncthreads();

    int w = t >> 6;
    int lane = t & 63;
    int quad = lane >> 4;
    int l16 = lane & 15;
    int rw = w * 16;

    f4_t acc[8];
#pragma unroll
    for (int j = 0; j < 8; j++) acc[j] = (f4_t){0.f, 0.f, 0.f, 0.f};

#pragma unroll
    for (int kk = 0; kk < 4; kk++) {
        int k0 = kk * 32;
        bf8_t a = __builtin_bit_cast(bf8_t,
            *(const short8*)&Xs[(rw + l16) * 136 + k0 + quad * 8]);
#pragma unroll
        for (int j = 0; j < 8; j++) {
            bf8_t b = __builtin_bit_cast(bf8_t,
                *(const short8*)&Ws[(j * 16 + l16) * 136 + k0 + quad * 8]);
            acc[j] = __builtin_amdgcn_mfma_f32_16x16x32_bf16(a, b, acc[j], 0, 0, 0);
        }
    }

#pragma unroll
    for (int reg = 0; reg < 4; reg++) {
        int r = row0 + rw + quad * 4 + reg;
        if (r < nrows) {
            float dv = dinv[r];
            float v0 = acc[0][reg] * dv, v1 = acc[1][reg] * dv;
            float v2 = acc[2][reg] * dv, v3 = acc[3][reg] * dv;
            float v4 = acc[4][reg] * dv, v5 = acc[5][reg] * dv;
            float v6 = acc[6][reg] * dv, v7 = acc[7][reg] * dv;
            int d0 = __builtin_amdgcn_cvt_pk_fp8_f32(v0, v1, 0, false);
            d0 = __builtin_amdgcn_cvt_pk_fp8_f32(v2, v3, d0, true);
            int d1 = __builtin_amdgcn_cvt_pk_fp8_f32(v4, v5, 0, false);
            d1 = __builtin_amdgcn_cvt_pk_fp8_f32(v6, v7, d1, true);
            *(uint2*)&Y[(size_t)r * DH + l16 * 8] = make_uint2((unsigned)d0, (unsigned)d1);
        }
    }
}

// ---------- Direct gather-accumulate aggregation ----------
// One dst node per wave; half-waves take alternate edges; each lane gathers
// one dword (4 fp8) of the source row, converts with v_cvt_pk_f32_fp8, and
// accumulates 4 floats. No LDS, no barriers, no MFMA. Neighbor indices are
// prefetched into registers (csr[s0+lane]) and broadcast via __shfl so the
// csr->row dependence is off the inner-loop critical path.
// T rows are in k_gemm's permuted byte order; sum commutes with the
// permutation, so we un-permute only at the store:
//   byte p = 4*l5+b  ->  true col = 64*(l5&1) + 16*b + (l5>>1).
__global__ __launch_bounds__(256) void k_agg(const unsigned char* __restrict__ T,
                                             unsigned short* __restrict__ Out,
                                             const float* __restrict__ dinv,
                                             const int* __restrict__ off,
                                             const int* __restrict__ csr,
                                             const float* __restrict__ bias,
                                             int elu, int N) {
    int t = threadIdx.x;
    int d = blockIdx.x * 4 + (t >> 6);
    if (d >= N) return;
    int lane = t & 63;
    int half = lane >> 5;
    int l5 = lane & 31;

    int s0 = off[d];
    int deg = off[d + 1] - s0;

    // prefetch up to 64 neighbor indices into registers (coalesced 256B)
    int jl = (lane < deg) ? csr[s0 + lane] : 0;

    float a0 = 0.f, a1 = 0.f, a2 = 0.f, a3 = 0.f;

    // self loop: half 0 loads own row, half 1 contributes fp8 zeros
    unsigned int vs = half ? 0u
        : *(const unsigned int*)(T + (size_t)d * DH + (l5 << 2));
    {
        f2_t lo = __builtin_amdgcn_cvt_pk_f32_fp8(vs, false);
        f2_t hi = __builtin_amdgcn_cvt_pk_f32_fp8(vs, true);
        a0 += lo[0]; a1 += lo[1]; a2 += hi[0]; a3 += hi[1];
    }

    int dcl = min(deg, 64);
    int k = half;
    for (; k + 2 < dcl; k += 4) {   // each half-wave: edges k, k+2 (4 in flight/wave)
        int j0 = __shfl(jl, k);
        int j1 = __shfl(jl, k + 2);
        unsigned int v0 = *(const unsigned int*)(T + (size_t)j0 * DH + (l5 << 2));
        unsigned int v1 = *(const unsigned int*)(T + (size_t)j1 * DH + (l5 << 2));
        f2_t lo0 = __builtin_amdgcn_cvt_pk_f32_fp8(v0, false);
        f2_t hi0 = __builtin_amdgcn_cvt_pk_f32_fp8(v0, true);
        f2_t lo1 = __builtin_amdgcn_cvt_pk_f32_fp8(v1, false);
        f2_t hi1 = __builtin_amdgcn_cvt_pk_f32_fp8(v1, true);
        a0 += lo0[0] + lo1[0];
        a1 += lo0[1] + lo1[1];
        a2 += hi0[0] + hi1[0];
        a3 += hi0[1] + hi1[1];
    }
    if (k < dcl) {                   // per-half tail (at most 1 edge)
        int j0 = __shfl(jl, k);
        unsigned int v0 = *(const unsigned int*)(T + (size_t)j0 * DH + (l5 << 2));
        f2_t lo0 = __builtin_amdgcn_cvt_pk_f32_fp8(v0, false);
        f2_t hi0 = __builtin_amdgcn_cvt_pk_f32_fp8(v0, true);
        a0 += lo0[0]; a1 += lo0[1]; a2 += hi0[0]; a3 += hi0[1];
    }
    // rare overflow path (degree > 64): direct csr loads
    for (int q = 64 + half; q < deg; q += 2) {
        int j = csr[s0 + q];
        unsigned int v0 = *(const unsigned int*)(T + (size_t)j * DH + (l5 << 2));
        f2_t lo0 = __builtin_amdgcn_cvt_pk_f32_fp8(v0, false);
        f2_t hi0 = __builtin_amdgcn_cvt_pk_f32_fp8(v0, true);
        a0 += lo0[0]; a1 += lo0[1]; a2 += hi0[0]; a3 += hi0[1];
    }

    // combine the two halves (lanes l and l+32 hold the same 4 byte-slots)
    a0 += __shfl_xor(a0, 32);
    a1 += __shfl_xor(a1, 32);
    a2 += __shfl_xor(a2, 32);
    a3 += __shfl_xor(a3, 32);

    if (half == 0) {
        float dv = dinv[d];
        int base = ((l5 & 1) << 6) | (l5 >> 1);   // true col of byte b=0
        float o0 = a0 * dv + bias[base];
        float o1 = a1 * dv + bias[base + 16];
        float o2 = a2 * dv + bias[base + 32];
        float o3 = a3 * dv + bias[base + 48];
        if (elu) {
            o0 = o0 > 0.f ? o0 : expm1f(o0);
            o1 = o1 > 0.f ? o1 : expm1f(o1);
            o2 = o2 > 0.f ? o2 : expm1f(o2);
            o3 = o3 > 0.f ? o3 : expm1f(o3);
        }
        unsigned short* orow = Out + (size_t)d * DH;
        orow[base]      = f2b(o0);
        orow[base + 16] = f2b(o1);
        orow[base + 32] = f2b(o2);
        orow[base + 48] = f2b(o3);
    }
}

// ---------- Mean pool: wave-per-row streaming, (G x 32) blocks, bf16 input ----------
__global__ __launch_bounds__(256) void k_pool(const unsigned int* __restrict__ H32,
                                              const int* __restrict__ batch,
                                              float* __restrict__ Gsum,
                                              int* __restrict__ cnts, int N) {
    int g = blockIdx.x;
    int p = blockIdx.y;
    int t = threadIdx.x;
    int lane = t & 63;
    int rg = t >> 6;  // wave 0..3
    int lo = 0, hi = N;
    while (lo < hi) { int m = (lo + hi) >> 1; if (batch[m] < g) lo = m + 1; else hi = m; }
    int s = lo;
    hi = N;
    while (lo < hi) { int m = (lo + hi) >> 1; if (batch[m] < g + 1) lo = m + 1; else hi = m; }
    int e = lo;
    int len = e - s;
    int parts = (int)gridDim.y;
    int chunk = (len + parts - 1) / parts;
    int i0 = s + p * chunk;
    int i1 = min(i0 + chunk, e);
    float a0 = 0.f, a1 = 0.f;
    for (int i = i0 + rg; i < i1; i += 4) {
        unsigned int v = H32[(size_t)i * 64 + lane];
        a0 += b2f((unsigned short)(v & 0xffffu));
        a1 += b2f((unsigned short)(v >> 16));
    }
    __shared__ float ps[4][DH];
    ps[rg][lane * 2] = a0;
    ps[rg][lane * 2 + 1] = a1;
    __syncthreads();
    if (t < DH) {
        float v = ps[0][t] + ps[1][t] + ps[2][t] + ps[3][t];
        atomicAdd(&Gsum[g * DH + t], v);
    }
    if (p == 0 && t == 0) cnts[g] = len;
}

// ---------- MLP head + log_softmax ----------
__global__ __launch_bounds__(64) void k_head(const float* __restrict__ Gsum,
                                             const int* __restrict__ cnts,
                                             const float* __restrict__ W1,
                                             const float* __restrict__ b1,
                                             const float* __restrict__ W2,
                                             const float* __restrict__ b2,
                                             float* __restrict__ out) {
    int g = blockIdx.x;
    int t = threadIdx.x;
    __shared__ float gv[DH];
    __shared__ float mid[20];
    __shared__ float o[10];
    float inv = 1.f / fmaxf((float)cnts[g], 1.f);
    for (int i = t; i < DH; i += 64) gv[i] = Gsum[g * DH + i] * inv;
    __syncthreads();
    if (t < 20) {
        float a = b1[t];
        for (int k = 0; k < DH; k++) a += gv[k] * W1[k * 20 + t];
        mid[t] = fmaxf(a, 0.f);
    }
    __syncthreads();
    if (t < 10) {
        float a = b2[t];
        for (int k = 0; k < 20; k++) a += mid[k] * W2[k * 10 + t];
        o[t] = a;
    }
    __syncthreads();
    if (t == 0) {
        float m = -1e30f;
        for (int j = 0; j < 10; j++) m = fmaxf(m, o[j]);
        float ssum = 0.f;
        for (int j = 0; j < 10; j++) ssum += expf(o[j] - m);
        float l = logf(ssum);
        for (int j = 0; j < 10; j++) out[g * 10 + j] = o[j] - m - l;
    }
}

extern "C" void kernel_launch(void* const* d_in, const int* in_sizes, int n_in,
                              void* d_out, int out_size, void* d_ws, size_t ws_size,
                              hipStream_t stream) {
    const float* x    = (const float*)d_in[0];
    const int*   ei   = (const int*)d_in[1];
    const int*   batch= (const int*)d_in[2];
    const float* W1   = (const float*)d_in[3];
    const float* b1   = (const float*)d_in[4];
    const float* W2   = (const float*)d_in[5];
    const float* b2   = (const float*)d_in[6];
    const float* fc1W = (const float*)d_in[7];
    const float* fc1b = (const float*)d_in[8];
    const float* fc2W = (const float*)d_in[9];
    const float* fc2b = (const float*)d_in[10];
    float* out = (float*)d_out;

    int N = in_sizes[0] / DH;     // 100000
    int E = in_sizes[1] / 2;      // 1600000
    int G = out_size / 10;        // 64

    char* p = (char*)d_ws;
    auto alloc = [&](size_t bytes) {
        char* r = p;
        p += (bytes + 255) & ~(size_t)255;
        return r;
    };
    unsigned char*  t8 = (unsigned char*)alloc((size_t)N * DH);      // fp8 hidden table
    unsigned short* a1 = (unsigned short*)alloc((size_t)N * DH * 2); // bf16 act (both layers)
    int*   csr  = (int*)alloc((size_t)E * 4);
    int*   off  = (int*)alloc((size_t)(N + 1) * 4);
    float* dinv = (float*)alloc((size_t)N * 4);
    int nbuck = (N + 511) >> 9;   // 196
    unsigned int* pairs = (unsigned int*)alloc((size_t)nbuck * BCAP * 4);
    unsigned short* Wt1 = (unsigned short*)alloc(DH * DH * 2);
    unsigned short* Wt2 = (unsigned short*)alloc(DH * DH * 2);
    float* Gsum = (float*)alloc((size_t)G * DH * 4);
    int*   bcur = (int*)alloc(256 * 16 * 4);
    int*   cnts = (int*)alloc((size_t)G * 4);

    const int* row = ei;       // message source
    const int* col = ei + E;   // aggregation target

    (void)hipMemsetAsync(Gsum, 0, (size_t)G * DH * 4 + 256 * 16 * 4, stream);

    const int chunk = 8192;
    int ablocks = (E + chunk - 1) / chunk;  // 196
    k_bucket<<<ablocks, 256, 0, stream>>>(row, col, E, nbuck, chunk, pairs, bcur);
    k_build<<<nbuck, 256, 0, stream>>>(pairs, bcur, nbuck, N, off, dinv, csr);
    k_prepW<<<128, 256, 0, stream>>>(W1, W2, Wt1, Wt2);

    int gblocks = (N + 63) / 64;
    int nblocks4 = (N + 3) / 4;   // one dst node per wave
    // layer 1
    k_gemm_mfma<<<gblocks, 256, 0, stream>>>(x, 0, Wt1, dinv, t8, N);
    k_agg<<<nblocks4, 256, 0, stream>>>(t8, a1, dinv, off, csr, b1, 1, N);
    // layer 2
    k_gemm_mfma<<<gblocks, 256, 0, stream>>>(a1, 1, Wt2, dinv, t8, N);
    k_agg<<<nblocks4, 256, 0, stream>>>(t8, a1, dinv, off, csr, b2, 0, N);

    dim3 pg(G, 32);
    k_pool<<<pg, 256, 0, stream>>>((const unsigned int*)a1, batch, Gsum, cnts, N);
    k_head<<<G, 64, 0, stream>>>(Gsum, cnts, fc1W, fc1b, fc2W, fc2b, out);
}

// Round 2
// 312.146 us; speedup vs baseline: 1.0553x; 1.0553x over previous
//
#include <hip/hip_runtime.h>
#include <math.h>

#define DH 128
#define BCAP 16384  // slots per 512-node bucket (mean ~8163, >20 sigma headroom)

typedef __bf16 bf8_t __attribute__((ext_vector_type(8)));
typedef short short8 __attribute__((ext_vector_type(8)));
typedef float f4_t __attribute__((ext_vector_type(4)));
typedef float f2_t __attribute__((ext_vector_type(2)));

__device__ inline unsigned short f2b(float f) {
    unsigned int u = __builtin_bit_cast(unsigned int, f);
    u = u + 0x7fffu + ((u >> 16) & 1u);  // RNE
    return (unsigned short)(u >> 16);
}
__device__ inline float b2f(unsigned short h) {
    return __builtin_bit_cast(float, (unsigned int)h << 16);
}

// ---------- Pass A: bucket edges by dst>>9 ----------
__global__ __launch_bounds__(256) void k_bucket(const int* __restrict__ row,
                                                const int* __restrict__ col,
                                                int E, int nbuck, int chunk,
                                                unsigned int* __restrict__ pairs,
                                                int* __restrict__ bcur) {
    __shared__ int lcnt[256];
    __shared__ int lbase[256];
    __shared__ unsigned int srec[8192];
    int t = threadIdx.x;
    int e0 = blockIdx.x * chunk;
    int e1 = min(e0 + chunk, E);
    lcnt[t] = 0;
    __syncthreads();
    for (int i = e0 + t; i < e1; i += 256) {
        int d = col[i];
        int b = d >> 9;
        int slot = atomicAdd(&lcnt[b], 1);
        srec[i - e0] = ((unsigned int)b << 22) | ((unsigned int)(d & 511) << 13)
                     | (unsigned int)slot;
    }
    __syncthreads();
    if (t < nbuck) {
        int c = lcnt[t];
        lbase[t] = (c > 0) ? atomicAdd(&bcur[t * 16], c) : 0;  // stride 16: 1 line/counter
    }
    __syncthreads();
    for (int i = e0 + t; i < e1; i += 256) {
        unsigned int r = srec[i - e0];
        int b = r >> 22;
        unsigned int dl = (r >> 13) & 511u;
        int slot = (int)(r & 8191u);
        int g = lbase[b] + slot;
        if (g < BCAP)
            pairs[(size_t)b * BCAP + g] = ((unsigned int)row[i] << 9) | dl;
    }
}

// ---------- Pass B: one block per bucket builds off/dinv/csr (LDS-local) ----------
__global__ __launch_bounds__(256) void k_build(const unsigned int* __restrict__ pairs,
                                               const int* __restrict__ bcur,
                                               int nbuck, int N,
                                               int* __restrict__ off,
                                               float* __restrict__ dinv,
                                               int* __restrict__ csr) {
    __shared__ int sb[256];
    __shared__ int cnt2[512];
    __shared__ int excl[512];
    __shared__ int curi[512];
    __shared__ int stmp[256];
    int b = blockIdx.x, t = threadIdx.x;
    sb[t] = (t < nbuck) ? min(bcur[t * 16], BCAP) : 0;
    __syncthreads();
    for (int d = 1; d < 256; d <<= 1) {
        int v = (t >= d) ? sb[t - d] : 0;
        __syncthreads();
        sb[t] += v;
        __syncthreads();
    }
    int base = (b == 0) ? 0 : sb[b - 1];
    int cnt = sb[b] - base;
    int node0 = b << 9;
    int nodes = min(512, N - node0);
    cnt2[t] = 0; cnt2[t + 256] = 0;
    __syncthreads();
    const unsigned int* pp = pairs + (size_t)b * BCAP;
    for (int i = t; i < cnt; i += 256)
        atomicAdd(&cnt2[pp[i] & 511u], 1);
    __syncthreads();
    stmp[t] = cnt2[2 * t] + cnt2[2 * t + 1];
    __syncthreads();
    for (int d = 1; d < 256; d <<= 1) {
        int v = (t >= d) ? stmp[t - d] : 0;
        __syncthreads();
        stmp[t] += v;
        __syncthreads();
    }
    int pre = (t == 0) ? 0 : stmp[t - 1];
    excl[2 * t] = pre;
    excl[2 * t + 1] = pre + cnt2[2 * t];
    __syncthreads();
    if (t < nodes) {
        off[node0 + t] = base + excl[t];
        dinv[node0 + t] = rsqrtf((float)(cnt2[t] + 1));
    }
    int t2 = t + 256;
    if (t2 < nodes) {
        off[node0 + t2] = base + excl[t2];
        dinv[node0 + t2] = rsqrtf((float)(cnt2[t2] + 1));
    }
    if (t == 0) off[node0 + nodes] = base + cnt;
    curi[t] = excl[t]; curi[t + 256] = excl[t + 256];
    __syncthreads();
    for (int i = t; i < cnt; i += 256) {
        unsigned int p = pp[i];
        int d = (int)(p & 511u);
        int slot = atomicAdd(&curi[d], 1);
        csr[base + slot] = (int)(p >> 9);
    }
}

// ---------- W prep: Wt[n][k] = bf16(W[k][n]); layer-2 k-order permuted ----------
// Layer-1 k_agg stores rows in permuted byte order: position p holds true col
// c(p) = (p&7)*16 + (p>>3). GEMM sums over k, so layer-2 weights are stored
// with the SAME k-permutation: Wt2[n][p(k)] = W2[k][n], p(k) = ((k&15)<<3)|(k>>4)
// (the inverse of c). Then layer-2 GEMM runs unchanged on permuted activations.
__global__ void k_prepW(const float* __restrict__ W1, const float* __restrict__ W2,
                        unsigned short* __restrict__ Wt1, unsigned short* __restrict__ Wt2) {
    int t = blockIdx.x * blockDim.x + threadIdx.x;  // 32768
    int v = t & 16383;
    int k = v >> 7, n = v & 127;
    if (t < 16384) {
        Wt1[n * DH + k] = f2b(W1[k * DH + n]);
    } else {
        int p = ((k & 15) << 3) | (k >> 4);
        Wt2[n * DH + p] = f2b(W2[k * DH + n]);
    }
}

// ---------- MFMA GEMM -> fp8 e4m3 table, lane-major permuted rows ----------
// Row r byte p = l16*8 + j holds col j*16+l16 of (X[r]@W)*dinv[r].
// Downstream stays in permuted space; un-permute happens only in k_head.
__global__ __launch_bounds__(256) void k_gemm_mfma(const void* __restrict__ Xin, int x_is_bf16,
                                                   const unsigned short* __restrict__ Wt,
                                                   const float* __restrict__ dinv,
                                                   unsigned char* __restrict__ Y, int nrows) {
    __shared__ unsigned short Xs[64 * 136];
    __shared__ unsigned short Ws[128 * 136];
    int t = threadIdx.x;
    int row0 = blockIdx.x * 64;

    for (int v = t; v < 128 * 32; v += 256) {
        int n = v >> 5, kq = v & 31;
        ushort4 w = ((const ushort4*)Wt)[v];
        *(ushort4*)&Ws[n * 136 + kq * 4] = w;
    }
    if (x_is_bf16) {
        const unsigned short* X = (const unsigned short*)Xin;
        for (int v = t; v < 64 * 32; v += 256) {
            int r = v >> 5, cq = v & 31;
            int gr = row0 + r;
            ushort4 h;
            if (gr < nrows) h = ((const ushort4*)X)[(size_t)gr * 32 + cq];
            else { h.x = 0; h.y = 0; h.z = 0; h.w = 0; }
            *(ushort4*)&Xs[r * 136 + cq * 4] = h;
        }
    } else {
        const float* X = (const float*)Xin;
        for (int v = t; v < 64 * 32; v += 256) {
            int r = v >> 5, cq = v & 31;
            int gr = row0 + r;
            ushort4 h;
            if (gr < nrows) {
                float4 xv = ((const float4*)X)[(size_t)gr * 32 + cq];
                h.x = f2b(xv.x); h.y = f2b(xv.y); h.z = f2b(xv.z); h.w = f2b(xv.w);
            } else { h.x = 0; h.y = 0; h.z = 0; h.w = 0; }
            *(ushort4*)&Xs[r * 136 + cq * 4] = h;
        }
    }
    __syncthreads();

    int w = t >> 6;
    int lane = t & 63;
    int quad = lane >> 4;
    int l16 = lane & 15;
    int rw = w * 16;

    f4_t acc[8];
#pragma unroll
    for (int j = 0; j < 8; j++) acc[j] = (f4_t){0.f, 0.f, 0.f, 0.f};

#pragma unroll
    for (int kk = 0; kk < 4; kk++) {
        int k0 = kk * 32;
        bf8_t a = __builtin_bit_cast(bf8_t,
            *(const short8*)&Xs[(rw + l16) * 136 + k0 + quad * 8]);
#pragma unroll
        for (int j = 0; j < 8; j++) {
            bf8_t b = __builtin_bit_cast(bf8_t,
                *(const short8*)&Ws[(j * 16 + l16) * 136 + k0 + quad * 8]);
            acc[j] = __builtin_amdgcn_mfma_f32_16x16x32_bf16(a, b, acc[j], 0, 0, 0);
        }
    }

#pragma unroll
    for (int reg = 0; reg < 4; reg++) {
        int r = row0 + rw + quad * 4 + reg;
        if (r < nrows) {
            float dv = dinv[r];
            float v0 = acc[0][reg] * dv, v1 = acc[1][reg] * dv;
            float v2 = acc[2][reg] * dv, v3 = acc[3][reg] * dv;
            float v4 = acc[4][reg] * dv, v5 = acc[5][reg] * dv;
            float v6 = acc[6][reg] * dv, v7 = acc[7][reg] * dv;
            int d0 = __builtin_amdgcn_cvt_pk_fp8_f32(v0, v1, 0, false);
            d0 = __builtin_amdgcn_cvt_pk_fp8_f32(v2, v3, d0, true);
            int d1 = __builtin_amdgcn_cvt_pk_fp8_f32(v4, v5, 0, false);
            d1 = __builtin_amdgcn_cvt_pk_fp8_f32(v6, v7, d1, true);
            *(uint2*)&Y[(size_t)r * DH + l16 * 8] = make_uint2((unsigned)d0, (unsigned)d1);
        }
    }
}

// ---------- Block-cooperative gather-accumulate aggregation ----------
// 16 dst nodes per block (contiguous csr slice). Stage off[17] + indices in
// LDS once (coalesced), one barrier. Each wave owns 4 nodes; half-waves take
// alternate edges (lane handles one dword = 4 fp8 of the 128B row). Index
// fetch = broadcast ds_read (2-way, conflict-free); 4 gathers in flight via
// 4-pair unroll; only accumulators carry the loop. Output stays in permuted
// byte order -> coalesced uint2 store (lanes 0..31 cover the 256B row).
__global__ __launch_bounds__(256) void k_agg(const unsigned char* __restrict__ T,
                                             unsigned short* __restrict__ Out,
                                             const float* __restrict__ dinv,
                                             const int* __restrict__ off,
                                             const int* __restrict__ csr,
                                             const float* __restrict__ bias,
                                             int elu, int N) {
    __shared__ int ofs[17];
    __shared__ int sidx[768];
    int t = threadIdx.x;
    int d0 = blockIdx.x * 16;
    if (t < 17) ofs[t] = off[min(d0 + t, N)];
    __syncthreads();
    int s0 = ofs[0];
    int cnt = ofs[16] - s0;
    int scnt = min(cnt, 768);
    for (int k = t; k < scnt; k += 256) sidx[k] = csr[s0 + k];
    __syncthreads();

    int w = t >> 6;
    int lane = t & 63;
    int half = lane >> 5;
    int l5 = lane & 31;
    const unsigned char* Tl = T + (l5 << 2);  // lane's dword within any row

    for (int ni = 0; ni < 4; ni++) {
        int nd = d0 + 4 * w + ni;
        if (nd >= N) break;
        int eL = ofs[4 * w + ni] - s0;
        int eH = ofs[4 * w + ni + 1] - s0;
        int deg = eH - eL;

        float a0, a1, a2, a3;
        {   // self loop: both halves load own row (same addr), half 1 zeroed
            unsigned int u = *(const unsigned int*)(Tl + ((size_t)nd << 7));
            if (half) u = 0;
            f2_t lo = __builtin_amdgcn_cvt_pk_f32_fp8(u, false);
            f2_t hi = __builtin_amdgcn_cvt_pk_f32_fp8(u, true);
            a0 = lo[0]; a1 = lo[1]; a2 = hi[0]; a3 = hi[1];
        }

        if (eH <= scnt) {
            int base_e = eL + half;
            int Pf = deg >> 1;       // full pairs (2 edges each)
            int P4 = Pf & ~3;
            int i = 0;
            for (; i < P4; i += 4) {   // 8 edges, 4 loads in flight
                int ea = base_e + 2 * i;
                int j0 = sidx[ea];
                int j1 = sidx[ea + 2];
                int j2 = sidx[ea + 4];
                int j3 = sidx[ea + 6];
                unsigned int u0 = *(const unsigned int*)(Tl + ((size_t)j0 << 7));
                unsigned int u1 = *(const unsigned int*)(Tl + ((size_t)j1 << 7));
                unsigned int u2 = *(const unsigned int*)(Tl + ((size_t)j2 << 7));
                unsigned int u3 = *(const unsigned int*)(Tl + ((size_t)j3 << 7));
                f2_t lo0 = __builtin_amdgcn_cvt_pk_f32_fp8(u0, false);
                f2_t hi0 = __builtin_amdgcn_cvt_pk_f32_fp8(u0, true);
                f2_t lo1 = __builtin_amdgcn_cvt_pk_f32_fp8(u1, false);
                f2_t hi1 = __builtin_amdgcn_cvt_pk_f32_fp8(u1, true);
                f2_t lo2 = __builtin_amdgcn_cvt_pk_f32_fp8(u2, false);
                f2_t hi2 = __builtin_amdgcn_cvt_pk_f32_fp8(u2, true);
                f2_t lo3 = __builtin_amdgcn_cvt_pk_f32_fp8(u3, false);
                f2_t hi3 = __builtin_amdgcn_cvt_pk_f32_fp8(u3, true);
                a0 += (lo0[0] + lo1[0]) + (lo2[0] + lo3[0]);
                a1 += (lo0[1] + lo1[1]) + (lo2[1] + lo3[1]);
                a2 += (hi0[0] + hi1[0]) + (hi2[0] + hi3[0]);
                a3 += (hi0[1] + hi1[1]) + (hi2[1] + hi3[1]);
            }
            for (; i < Pf; i++) {
                int j0 = sidx[base_e + 2 * i];
                unsigned int u0 = *(const unsigned int*)(Tl + ((size_t)j0 << 7));
                f2_t lo = __builtin_amdgcn_cvt_pk_f32_fp8(u0, false);
                f2_t hi = __builtin_amdgcn_cvt_pk_f32_fp8(u0, true);
                a0 += lo[0]; a1 += lo[1]; a2 += hi[0]; a3 += hi[1];
            }
            if (deg & 1) {   // odd edge: both halves load it, half 1 zeroed
                int j0 = sidx[eL + deg - 1];
                unsigned int u0 = *(const unsigned int*)(Tl + ((size_t)j0 << 7));
                if (half) u0 = 0;
                f2_t lo = __builtin_amdgcn_cvt_pk_f32_fp8(u0, false);
                f2_t hi = __builtin_amdgcn_cvt_pk_f32_fp8(u0, true);
                a0 += lo[0]; a1 += lo[1]; a2 += hi[0]; a3 += hi[1];
            }
        } else {
            // rare overflow (block slice > 768 edges): read csr directly
            int gb = s0 + eL + half;
            int Pf = deg >> 1;
            for (int i = 0; i < Pf; i++) {
                int j0 = csr[gb + 2 * i];
                unsigned int u0 = *(const unsigned int*)(Tl + ((size_t)j0 << 7));
                f2_t lo = __builtin_amdgcn_cvt_pk_f32_fp8(u0, false);
                f2_t hi = __builtin_amdgcn_cvt_pk_f32_fp8(u0, true);
                a0 += lo[0]; a1 += lo[1]; a2 += hi[0]; a3 += hi[1];
            }
            if (deg & 1) {
                int j0 = csr[s0 + eL + deg - 1];
                unsigned int u0 = *(const unsigned int*)(Tl + ((size_t)j0 << 7));
                if (half) u0 = 0;
                f2_t lo = __builtin_amdgcn_cvt_pk_f32_fp8(u0, false);
                f2_t hi = __builtin_amdgcn_cvt_pk_f32_fp8(u0, true);
                a0 += lo[0]; a1 += lo[1]; a2 += hi[0]; a3 += hi[1];
            }
        }

        // combine the two halves (lanes l and l+32 hold the same byte slots)
        a0 += __shfl_xor(a0, 32);
        a1 += __shfl_xor(a1, 32);
        a2 += __shfl_xor(a2, 32);
        a3 += __shfl_xor(a3, 32);

        if (!half) {
            float dv = dinv[nd];
            // permuted slot p = 4*l5+b holds true col 64*(l5&1) + 16*b + (l5>>1)
            int c0 = ((l5 & 1) << 6) | (l5 >> 1);
            float o0 = a0 * dv + bias[c0];
            float o1 = a1 * dv + bias[c0 + 16];
            float o2 = a2 * dv + bias[c0 + 32];
            float o3 = a3 * dv + bias[c0 + 48];
            if (elu) {
                o0 = o0 > 0.f ? o0 : expm1f(o0);
                o1 = o1 > 0.f ? o1 : expm1f(o1);
                o2 = o2 > 0.f ? o2 : expm1f(o2);
                o3 = o3 > 0.f ? o3 : expm1f(o3);
            }
            unsigned int p0 = (unsigned int)f2b(o0) | ((unsigned int)f2b(o1) << 16);
            unsigned int p1 = (unsigned int)f2b(o2) | ((unsigned int)f2b(o3) << 16);
            *(uint2*)&Out[(size_t)nd * DH + (l5 << 2)] = make_uint2(p0, p1);
        }
    }
}

// ---------- Mean pool: wave-per-row streaming, (G x 32) blocks, bf16 input ----------
// Input rows are in permuted byte order; Gsum stays permuted (k_head fixes).
__global__ __launch_bounds__(256) void k_pool(const unsigned int* __restrict__ H32,
                                              const int* __restrict__ batch,
                                              float* __restrict__ Gsum,
                                              int* __restrict__ cnts, int N) {
    int g = blockIdx.x;
    int p = blockIdx.y;
    int t = threadIdx.x;
    int lane = t & 63;
    int rg = t >> 6;  // wave 0..3
    int lo = 0, hi = N;
    while (lo < hi) { int m = (lo + hi) >> 1; if (batch[m] < g) lo = m + 1; else hi = m; }
    int s = lo;
    hi = N;
    while (lo < hi) { int m = (lo + hi) >> 1; if (batch[m] < g + 1) lo = m + 1; else hi = m; }
    int e = lo;
    int len = e - s;
    int parts = (int)gridDim.y;
    int chunk = (len + parts - 1) / parts;
    int i0 = s + p * chunk;
    int i1 = min(i0 + chunk, e);
    float a0 = 0.f, a1 = 0.f;
    for (int i = i0 + rg; i < i1; i += 4) {
        unsigned int v = H32[(size_t)i * 64 + lane];
        a0 += b2f((unsigned short)(v & 0xffffu));
        a1 += b2f((unsigned short)(v >> 16));
    }
    __shared__ float ps[4][DH];
    ps[rg][lane * 2] = a0;
    ps[rg][lane * 2 + 1] = a1;
    __syncthreads();
    if (t < DH) {
        float v = ps[0][t] + ps[1][t] + ps[2][t] + ps[3][t];
        atomicAdd(&Gsum[g * DH + t], v);
    }
    if (p == 0 && t == 0) cnts[g] = len;
}

// ---------- MLP head + log_softmax (un-permutes Gsum on load) ----------
__global__ __launch_bounds__(64) void k_head(const float* __restrict__ Gsum,
                                             const int* __restrict__ cnts,
                                             const float* __restrict__ W1,
                                             const float* __restrict__ b1,
                                             const float* __restrict__ W2,
                                             const float* __restrict__ b2,
                                             float* __restrict__ out) {
    int g = blockIdx.x;
    int t = threadIdx.x;
    __shared__ float gv[DH];
    __shared__ float mid[20];
    __shared__ float o[10];
    float inv = 1.f / fmaxf((float)cnts[g], 1.f);
    for (int i = t; i < DH; i += 64) {
        int c = ((i & 7) << 4) | (i >> 3);   // true col of permuted pos i
        gv[c] = Gsum[g * DH + i] * inv;
    }
    __syncthreads();
    if (t < 20) {
        float a = b1[t];
        for (int k = 0; k < DH; k++) a += gv[k] * W1[k * 20 + t];
        mid[t] = fmaxf(a, 0.f);
    }
    __syncthreads();
    if (t < 10) {
        float a = b2[t];
        for (int k = 0; k < 20; k++) a += mid[k] * W2[k * 10 + t];
        o[t] = a;
    }
    __syncthreads();
    if (t == 0) {
        float m = -1e30f;
        for (int j = 0; j < 10; j++) m = fmaxf(m, o[j]);
        float ssum = 0.f;
        for (int j = 0; j < 10; j++) ssum += expf(o[j] - m);
        float l = logf(ssum);
        for (int j = 0; j < 10; j++) out[g * 10 + j] = o[j] - m - l;
    }
}

extern "C" void kernel_launch(void* const* d_in, const int* in_sizes, int n_in,
                              void* d_out, int out_size, void* d_ws, size_t ws_size,
                              hipStream_t stream) {
    const float* x    = (const float*)d_in[0];
    const int*   ei   = (const int*)d_in[1];
    const int*   batch= (const int*)d_in[2];
    const float* W1   = (const float*)d_in[3];
    const float* b1   = (const float*)d_in[4];
    const float* W2   = (const float*)d_in[5];
    const float* b2   = (const float*)d_in[6];
    const float* fc1W = (const float*)d_in[7];
    const float* fc1b = (const float*)d_in[8];
    const float* fc2W = (const float*)d_in[9];
    const float* fc2b = (const float*)d_in[10];
    float* out = (float*)d_out;

    int N = in_sizes[0] / DH;     // 100000
    int E = in_sizes[1] / 2;      // 1600000
    int G = out_size / 10;        // 64

    char* p = (char*)d_ws;
    auto alloc = [&](size_t bytes) {
        char* r = p;
        p += (bytes + 255) & ~(size_t)255;
        return r;
    };
    unsigned char*  t8 = (unsigned char*)alloc((size_t)N * DH);      // fp8 hidden table
    unsigned short* a1 = (unsigned short*)alloc((size_t)N * DH * 2); // bf16 act (both layers)
    int*   csr  = (int*)alloc((size_t)E * 4);
    int*   off  = (int*)alloc((size_t)(N + 1) * 4);
    float* dinv = (float*)alloc((size_t)N * 4);
    int nbuck = (N + 511) >> 9;   // 196
    unsigned int* pairs = (unsigned int*)alloc((size_t)nbuck * BCAP * 4);
    unsigned short* Wt1 = (unsigned short*)alloc(DH * DH * 2);
    unsigned short* Wt2 = (unsigned short*)alloc(DH * DH * 2);
    float* Gsum = (float*)alloc((size_t)G * DH * 4);
    int*   bcur = (int*)alloc(256 * 16 * 4);
    int*   cnts = (int*)alloc((size_t)G * 4);

    const int* row = ei;       // message source
    const int* col = ei + E;   // aggregation target

    (void)hipMemsetAsync(Gsum, 0, (size_t)G * DH * 4 + 256 * 16 * 4, stream);

    const int chunk = 8192;
    int ablocks = (E + chunk - 1) / chunk;  // 196
    k_bucket<<<ablocks, 256, 0, stream>>>(row, col, E, nbuck, chunk, pairs, bcur);
    k_build<<<nbuck, 256, 0, stream>>>(pairs, bcur, nbuck, N, off, dinv, csr);
    k_prepW<<<128, 256, 0, stream>>>(W1, W2, Wt1, Wt2);

    int gblocks = (N + 63) / 64;
    int mblocks = (N + 15) / 16;  // 6250
    // layer 1
    k_gemm_mfma<<<gblocks, 256, 0, stream>>>(x, 0, Wt1, dinv, t8, N);
    k_agg<<<mblocks, 256, 0, stream>>>(t8, a1, dinv, off, csr, b1, 1, N);
    // layer 2
    k_gemm_mfma<<<gblocks, 256, 0, stream>>>(a1, 1, Wt2, dinv, t8, N);
    k_agg<<<mblocks, 256, 0, stream>>>(t8, a1, dinv, off, csr, b2, 0, N);

    dim3 pg(G, 32);
    k_pool<<<pg, 256, 0, stream>>>((const unsigned int*)a1, batch, Gsum, cnts, N);
    k_head<<<G, 64, 0, stream>>>(Gsum, cnts, fc1W, fc1b, fc2W, fc2b, out);
}

// Round 3
// 303.526 us; speedup vs baseline: 1.0853x; 1.0284x over previous
//
#include <hip/hip_runtime.h>
#include <math.h>

#define DH 128
#define BCAP 16384  // slots per 512-node bucket (mean ~8163, >20 sigma headroom)

typedef __bf16 bf8_t __attribute__((ext_vector_type(8)));
typedef short short8 __attribute__((ext_vector_type(8)));
typedef float f4_t __attribute__((ext_vector_type(4)));
typedef float f2_t __attribute__((ext_vector_type(2)));

__device__ inline unsigned short f2b(float f) {
    unsigned int u = __builtin_bit_cast(unsigned int, f);
    u = u + 0x7fffu + ((u >> 16) & 1u);  // RNE
    return (unsigned short)(u >> 16);
}
__device__ inline float b2f(unsigned short h) {
    return __builtin_bit_cast(float, (unsigned int)h << 16);
}

// ---------- Pass A: bucket edges by dst>>9 ----------
__global__ __launch_bounds__(256) void k_bucket(const int* __restrict__ row,
                                                const int* __restrict__ col,
                                                int E, int nbuck, int chunk,
                                                unsigned int* __restrict__ pairs,
                                                int* __restrict__ bcur) {
    __shared__ int lcnt[256];
    __shared__ int lbase[256];
    __shared__ unsigned int srec[8192];
    int t = threadIdx.x;
    int e0 = blockIdx.x * chunk;
    int e1 = min(e0 + chunk, E);
    lcnt[t] = 0;
    __syncthreads();
    for (int i = e0 + t; i < e1; i += 256) {
        int d = col[i];
        int b = d >> 9;
        int slot = atomicAdd(&lcnt[b], 1);
        srec[i - e0] = ((unsigned int)b << 22) | ((unsigned int)(d & 511) << 13)
                     | (unsigned int)slot;
    }
    __syncthreads();
    if (t < nbuck) {
        int c = lcnt[t];
        lbase[t] = (c > 0) ? atomicAdd(&bcur[t * 16], c) : 0;  // stride 16: 1 line/counter
    }
    __syncthreads();
    for (int i = e0 + t; i < e1; i += 256) {
        unsigned int r = srec[i - e0];
        int b = r >> 22;
        unsigned int dl = (r >> 13) & 511u;
        int slot = (int)(r & 8191u);
        int g = lbase[b] + slot;
        if (g < BCAP)
            pairs[(size_t)b * BCAP + g] = ((unsigned int)row[i] << 9) | dl;
    }
}

// ---------- Pass B: one block per bucket builds off/dinv/csr (LDS-local) ----------
__global__ __launch_bounds__(256) void k_build(const unsigned int* __restrict__ pairs,
                                               const int* __restrict__ bcur,
                                               int nbuck, int N,
                                               int* __restrict__ off,
                                               float* __restrict__ dinv,
                                               int* __restrict__ csr) {
    __shared__ int sb[256];
    __shared__ int cnt2[512];
    __shared__ int excl[512];
    __shared__ int curi[512];
    __shared__ int stmp[256];
    int b = blockIdx.x, t = threadIdx.x;
    sb[t] = (t < nbuck) ? min(bcur[t * 16], BCAP) : 0;
    __syncthreads();
    for (int d = 1; d < 256; d <<= 1) {
        int v = (t >= d) ? sb[t - d] : 0;
        __syncthreads();
        sb[t] += v;
        __syncthreads();
    }
    int base = (b == 0) ? 0 : sb[b - 1];
    int cnt = sb[b] - base;
    int node0 = b << 9;
    int nodes = min(512, N - node0);
    cnt2[t] = 0; cnt2[t + 256] = 0;
    __syncthreads();
    const unsigned int* pp = pairs + (size_t)b * BCAP;
    for (int i = t; i < cnt; i += 256)
        atomicAdd(&cnt2[pp[i] & 511u], 1);
    __syncthreads();
    stmp[t] = cnt2[2 * t] + cnt2[2 * t + 1];
    __syncthreads();
    for (int d = 1; d < 256; d <<= 1) {
        int v = (t >= d) ? stmp[t - d] : 0;
        __syncthreads();
        stmp[t] += v;
        __syncthreads();
    }
    int pre = (t == 0) ? 0 : stmp[t - 1];
    excl[2 * t] = pre;
    excl[2 * t + 1] = pre + cnt2[2 * t];
    __syncthreads();
    if (t < nodes) {
        off[node0 + t] = base + excl[t];
        dinv[node0 + t] = rsqrtf((float)(cnt2[t] + 1));
    }
    int t2 = t + 256;
    if (t2 < nodes) {
        off[node0 + t2] = base + excl[t2];
        dinv[node0 + t2] = rsqrtf((float)(cnt2[t2] + 1));
    }
    if (t == 0) off[node0 + nodes] = base + cnt;
    curi[t] = excl[t]; curi[t + 256] = excl[t + 256];
    __syncthreads();
    for (int i = t; i < cnt; i += 256) {
        unsigned int p = pp[i];
        int d = (int)(p & 511u);
        int slot = atomicAdd(&curi[d], 1);
        csr[base + slot] = (int)(p >> 9);
    }
}

// ---------- W prep: Wt[n][k] = bf16(W[k][n]); layer-2 k-order permuted ----------
// Layer-1 k_agg stores rows in permuted byte order: position p holds true col
// c(p) = (p&7)*16 + (p>>3). GEMM sums over k, so layer-2 weights are stored
// with the SAME k-permutation: Wt2[n][p(k)] = W2[k][n], p(k) = ((k&15)<<3)|(k>>4)
// (the inverse of c). Then layer-2 GEMM runs unchanged on permuted activations.
__global__ void k_prepW(const float* __restrict__ W1, const float* __restrict__ W2,
                        unsigned short* __restrict__ Wt1, unsigned short* __restrict__ Wt2) {
    int t = blockIdx.x * blockDim.x + threadIdx.x;  // 32768
    int v = t & 16383;
    int k = v >> 7, n = v & 127;
    if (t < 16384) {
        Wt1[n * DH + k] = f2b(W1[k * DH + n]);
    } else {
        int p = ((k & 15) << 3) | (k >> 4);
        Wt2[n * DH + p] = f2b(W2[k * DH + n]);
    }
}

// ---------- MFMA GEMM -> fp8 e4m3 table, lane-major permuted rows ----------
// Row r byte p = l16*8 + j holds col j*16+l16 of (X[r]@W)*dinv[r].
// Downstream stays in permuted space; un-permute happens only in k_head.
__global__ __launch_bounds__(256) void k_gemm_mfma(const void* __restrict__ Xin, int x_is_bf16,
                                                   const unsigned short* __restrict__ Wt,
                                                   const float* __restrict__ dinv,
                                                   unsigned char* __restrict__ Y, int nrows) {
    __shared__ unsigned short Xs[64 * 136];
    __shared__ unsigned short Ws[128 * 136];
    int t = threadIdx.x;
    int row0 = blockIdx.x * 64;

    for (int v = t; v < 128 * 32; v += 256) {
        int n = v >> 5, kq = v & 31;
        ushort4 w = ((const ushort4*)Wt)[v];
        *(ushort4*)&Ws[n * 136 + kq * 4] = w;
    }
    if (x_is_bf16) {
        const unsigned short* X = (const unsigned short*)Xin;
        for (int v = t; v < 64 * 32; v += 256) {
            int r = v >> 5, cq = v & 31;
            int gr = row0 + r;
            ushort4 h;
            if (gr < nrows) h = ((const ushort4*)X)[(size_t)gr * 32 + cq];
            else { h.x = 0; h.y = 0; h.z = 0; h.w = 0; }
            *(ushort4*)&Xs[r * 136 + cq * 4] = h;
        }
    } else {
        const float* X = (const float*)Xin;
        for (int v = t; v < 64 * 32; v += 256) {
            int r = v >> 5, cq = v & 31;
            int gr = row0 + r;
            ushort4 h;
            if (gr < nrows) {
                float4 xv = ((const float4*)X)[(size_t)gr * 32 + cq];
                h.x = f2b(xv.x); h.y = f2b(xv.y); h.z = f2b(xv.z); h.w = f2b(xv.w);
            } else { h.x = 0; h.y = 0; h.z = 0; h.w = 0; }
            *(ushort4*)&Xs[r * 136 + cq * 4] = h;
        }
    }
    __syncthreads();

    int w = t >> 6;
    int lane = t & 63;
    int quad = lane >> 4;
    int l16 = lane & 15;
    int rw = w * 16;

    f4_t acc[8];
#pragma unroll
    for (int j = 0; j < 8; j++) acc[j] = (f4_t){0.f, 0.f, 0.f, 0.f};

#pragma unroll
    for (int kk = 0; kk < 4; kk++) {
        int k0 = kk * 32;
        bf8_t a = __builtin_bit_cast(bf8_t,
            *(const short8*)&Xs[(rw + l16) * 136 + k0 + quad * 8]);
#pragma unroll
        for (int j = 0; j < 8; j++) {
            bf8_t b = __builtin_bit_cast(bf8_t,
                *(const short8*)&Ws[(j * 16 + l16) * 136 + k0 + quad * 8]);
            acc[j] = __builtin_amdgcn_mfma_f32_16x16x32_bf16(a, b, acc[j], 0, 0, 0);
        }
    }

#pragma unroll
    for (int reg = 0; reg < 4; reg++) {
        int r = row0 + rw + quad * 4 + reg;
        if (r < nrows) {
            float dv = dinv[r];
            float v0 = acc[0][reg] * dv, v1 = acc[1][reg] * dv;
            float v2 = acc[2][reg] * dv, v3 = acc[3][reg] * dv;
            float v4 = acc[4][reg] * dv, v5 = acc[5][reg] * dv;
            float v6 = acc[6][reg] * dv, v7 = acc[7][reg] * dv;
            int d0 = __builtin_amdgcn_cvt_pk_fp8_f32(v0, v1, 0, false);
            d0 = __builtin_amdgcn_cvt_pk_fp8_f32(v2, v3, d0, true);
            int d1 = __builtin_amdgcn_cvt_pk_fp8_f32(v4, v5, 0, false);
            d1 = __builtin_amdgcn_cvt_pk_fp8_f32(v6, v7, d1, true);
            *(uint2*)&Y[(size_t)r * DH + l16 * 8] = make_uint2((unsigned)d0, (unsigned)d1);
        }
    }
}

// ---------- Block-cooperative gather-accumulate aggregation (v3) ----------
// 16 dst nodes/block; off[17] + csr slice + dinv staged in LDS once. Wave owns
// 4 nodes; half-waves take alternate edges (lane = one dword of the 128B row).
// v3: f2_t accumulators (v_pk_add_f32), 32-bit saddr gather addressing,
// 8 loads in flight, bias hoisted to registers, cheap ELU.
__global__ __launch_bounds__(256) void k_agg(const unsigned char* __restrict__ T,
                                             unsigned short* __restrict__ Out,
                                             const float* __restrict__ dinv,
                                             const int* __restrict__ off,
                                             const int* __restrict__ csr,
                                             const float* __restrict__ bias,
                                             int elu, int N) {
    __shared__ int ofs[17];
    __shared__ float dv16[16];
    __shared__ int sidx[768];
    int t = threadIdx.x;
    int d0 = blockIdx.x * 16;
    if (t < 17) ofs[t] = off[min(d0 + t, N)];
    if (t >= 32 && t < 48) dv16[t - 32] = dinv[min(d0 + t - 32, N - 1)];
    __syncthreads();
    int s0 = ofs[0];
    int cnt = ofs[16] - s0;
    int scnt = min(cnt, 768);
    for (int k = t; k < scnt; k += 256) sidx[k] = csr[s0 + k];
    __syncthreads();

    int w = t >> 6;
    int lane = t & 63;
    int half = lane >> 5;
    int l5 = lane & 31;
    const unsigned int* Tw = (const unsigned int*)T;  // row j, lane dword: (j<<5)+l5

    // permuted slot p = 4*l5+b holds true col 64*(l5&1) + 16*b + (l5>>1)
    int c0 = ((l5 & 1) << 6) | (l5 >> 1);
    float bb0 = bias[c0], bb1 = bias[c0 + 16], bb2 = bias[c0 + 32], bb3 = bias[c0 + 48];

    for (int ni = 0; ni < 4; ni++) {
        int nl = 4 * w + ni;
        int nd = d0 + nl;
        if (nd >= N) break;
        int eL = ofs[nl] - s0;
        int eH = ofs[nl + 1] - s0;
        int deg = eH - eL;

        f2_t acc01, acc23;
        {   // self loop: both halves load own row (same addr), half 1 zeroed
            unsigned int u = Tw[(nd << 5) + l5];
            if (half) u = 0;
            acc01 = __builtin_amdgcn_cvt_pk_f32_fp8(u, false);
            acc23 = __builtin_amdgcn_cvt_pk_f32_fp8(u, true);
        }

        if (eH <= scnt) {
            int be = eL + half;
            int Pf = deg >> 1;       // per-half edge count (full pairs)
            int i = 0;
            for (; i + 8 <= Pf; i += 8) {   // 16 edges, 8 loads in flight
                int ea = be + 2 * i;
                int j0 = sidx[ea];      int j1 = sidx[ea + 2];
                int j2 = sidx[ea + 4];  int j3 = sidx[ea + 6];
                int j4 = sidx[ea + 8];  int j5 = sidx[ea + 10];
                int j6 = sidx[ea + 12]; int j7 = sidx[ea + 14];
                unsigned int u0 = Tw[(j0 << 5) + l5];
                unsigned int u1 = Tw[(j1 << 5) + l5];
                unsigned int u2 = Tw[(j2 << 5) + l5];
                unsigned int u3 = Tw[(j3 << 5) + l5];
                unsigned int u4 = Tw[(j4 << 5) + l5];
                unsigned int u5 = Tw[(j5 << 5) + l5];
                unsigned int u6 = Tw[(j6 << 5) + l5];
                unsigned int u7 = Tw[(j7 << 5) + l5];
                acc01 += __builtin_amdgcn_cvt_pk_f32_fp8(u0, false);
                acc23 += __builtin_amdgcn_cvt_pk_f32_fp8(u0, true);
                acc01 += __builtin_amdgcn_cvt_pk_f32_fp8(u1, false);
                acc23 += __builtin_amdgcn_cvt_pk_f32_fp8(u1, true);
                acc01 += __builtin_amdgcn_cvt_pk_f32_fp8(u2, false);
                acc23 += __builtin_amdgcn_cvt_pk_f32_fp8(u2, true);
                acc01 += __builtin_amdgcn_cvt_pk_f32_fp8(u3, false);
                acc23 += __builtin_amdgcn_cvt_pk_f32_fp8(u3, true);
                acc01 += __builtin_amdgcn_cvt_pk_f32_fp8(u4, false);
                acc23 += __builtin_amdgcn_cvt_pk_f32_fp8(u4, true);
                acc01 += __builtin_amdgcn_cvt_pk_f32_fp8(u5, false);
                acc23 += __builtin_amdgcn_cvt_pk_f32_fp8(u5, true);
                acc01 += __builtin_amdgcn_cvt_pk_f32_fp8(u6, false);
                acc23 += __builtin_amdgcn_cvt_pk_f32_fp8(u6, true);
                acc01 += __builtin_amdgcn_cvt_pk_f32_fp8(u7, false);
                acc23 += __builtin_amdgcn_cvt_pk_f32_fp8(u7, true);
            }
            for (; i + 4 <= Pf; i += 4) {
                int ea = be + 2 * i;
                int j0 = sidx[ea];     int j1 = sidx[ea + 2];
                int j2 = sidx[ea + 4]; int j3 = sidx[ea + 6];
                unsigned int u0 = Tw[(j0 << 5) + l5];
                unsigned int u1 = Tw[(j1 << 5) + l5];
                unsigned int u2 = Tw[(j2 << 5) + l5];
                unsigned int u3 = Tw[(j3 << 5) + l5];
                acc01 += __builtin_amdgcn_cvt_pk_f32_fp8(u0, false);
                acc23 += __builtin_amdgcn_cvt_pk_f32_fp8(u0, true);
                acc01 += __builtin_amdgcn_cvt_pk_f32_fp8(u1, false);
                acc23 += __builtin_amdgcn_cvt_pk_f32_fp8(u1, true);
                acc01 += __builtin_amdgcn_cvt_pk_f32_fp8(u2, false);
                acc23 += __builtin_amdgcn_cvt_pk_f32_fp8(u2, true);
                acc01 += __builtin_amdgcn_cvt_pk_f32_fp8(u3, false);
                acc23 += __builtin_amdgcn_cvt_pk_f32_fp8(u3, true);
            }
            for (; i < Pf; i++) {
                int j0 = sidx[be + 2 * i];
                unsigned int u0 = Tw[(j0 << 5) + l5];
                acc01 += __builtin_amdgcn_cvt_pk_f32_fp8(u0, false);
                acc23 += __builtin_amdgcn_cvt_pk_f32_fp8(u0, true);
            }
            if (deg & 1) {   // odd edge: both halves load it, half 1 zeroed
                int j0 = sidx[eL + deg - 1];
                unsigned int u0 = Tw[(j0 << 5) + l5];
                if (half) u0 = 0;
                acc01 += __builtin_amdgcn_cvt_pk_f32_fp8(u0, false);
                acc23 += __builtin_amdgcn_cvt_pk_f32_fp8(u0, true);
            }
        } else {
            // rare overflow (block slice > 768 edges): read csr directly
            int gb = s0 + eL + half;
            int Pf = deg >> 1;
            for (int i = 0; i < Pf; i++) {
                int j0 = csr[gb + 2 * i];
                unsigned int u0 = Tw[(j0 << 5) + l5];
                acc01 += __builtin_amdgcn_cvt_pk_f32_fp8(u0, false);
                acc23 += __builtin_amdgcn_cvt_pk_f32_fp8(u0, true);
            }
            if (deg & 1) {
                int j0 = csr[s0 + eL + deg - 1];
                unsigned int u0 = Tw[(j0 << 5) + l5];
                if (half) u0 = 0;
                acc01 += __builtin_amdgcn_cvt_pk_f32_fp8(u0, false);
                acc23 += __builtin_amdgcn_cvt_pk_f32_fp8(u0, true);
            }
        }

        // combine halves (lanes l and l+32 hold the same byte slots)
        float a0 = acc01[0], a1 = acc01[1], a2 = acc23[0], a3 = acc23[1];
        a0 += __shfl_xor(a0, 32);
        a1 += __shfl_xor(a1, 32);
        a2 += __shfl_xor(a2, 32);
        a3 += __shfl_xor(a3, 32);

        if (!half) {
            float dv = dv16[nl];
            float o0 = a0 * dv + bb0;
            float o1 = a1 * dv + bb1;
            float o2 = a2 * dv + bb2;
            float o3 = a3 * dv + bb3;
            if (elu) {
                o0 = o0 > 0.f ? o0 : __expf(o0) - 1.f;
                o1 = o1 > 0.f ? o1 : __expf(o1) - 1.f;
                o2 = o2 > 0.f ? o2 : __expf(o2) - 1.f;
                o3 = o3 > 0.f ? o3 : __expf(o3) - 1.f;
            }
            unsigned int p0 = (unsigned int)f2b(o0) | ((unsigned int)f2b(o1) << 16);
            unsigned int p1 = (unsigned int)f2b(o2) | ((unsigned int)f2b(o3) << 16);
            *(uint2*)&Out[(size_t)nd * DH + (l5 << 2)] = make_uint2(p0, p1);
        }
    }
}

// ---------- Mean pool: wave-per-row streaming, (G x 32) blocks, bf16 input ----------
// Input rows are in permuted byte order; Gsum stays permuted (k_head fixes).
__global__ __launch_bounds__(256) void k_pool(const unsigned int* __restrict__ H32,
                                              const int* __restrict__ batch,
                                              float* __restrict__ Gsum,
                                              int* __restrict__ cnts, int N) {
    int g = blockIdx.x;
    int p = blockIdx.y;
    int t = threadIdx.x;
    int lane = t & 63;
    int rg = t >> 6;  // wave 0..3
    int lo = 0, hi = N;
    while (lo < hi) { int m = (lo + hi) >> 1; if (batch[m] < g) lo = m + 1; else hi = m; }
    int s = lo;
    hi = N;
    while (lo < hi) { int m = (lo + hi) >> 1; if (batch[m] < g + 1) lo = m + 1; else hi = m; }
    int e = lo;
    int len = e - s;
    int parts = (int)gridDim.y;
    int chunk = (len + parts - 1) / parts;
    int i0 = s + p * chunk;
    int i1 = min(i0 + chunk, e);
    float a0 = 0.f, a1 = 0.f;
    for (int i = i0 + rg; i < i1; i += 4) {
        unsigned int v = H32[(size_t)i * 64 + lane];
        a0 += b2f((unsigned short)(v & 0xffffu));
        a1 += b2f((unsigned short)(v >> 16));
    }
    __shared__ float ps[4][DH];
    ps[rg][lane * 2] = a0;
    ps[rg][lane * 2 + 1] = a1;
    __syncthreads();
    if (t < DH) {
        float v = ps[0][t] + ps[1][t] + ps[2][t] + ps[3][t];
        atomicAdd(&Gsum[g * DH + t], v);
    }
    if (p == 0 && t == 0) cnts[g] = len;
}

// ---------- MLP head + log_softmax (un-permutes Gsum on load) ----------
__global__ __launch_bounds__(64) void k_head(const float* __restrict__ Gsum,
                                             const int* __restrict__ cnts,
                                             const float* __restrict__ W1,
                                             const float* __restrict__ b1,
                                             const float* __restrict__ W2,
                                             const float* __restrict__ b2,
                                             float* __restrict__ out) {
    int g = blockIdx.x;
    int t = threadIdx.x;
    __shared__ float gv[DH];
    __shared__ float mid[20];
    __shared__ float o[10];
    float inv = 1.f / fmaxf((float)cnts[g], 1.f);
    for (int i = t; i < DH; i += 64) {
        int c = ((i & 7) << 4) | (i >> 3);   // true col of permuted pos i
        gv[c] = Gsum[g * DH + i] * inv;
    }
    __syncthreads();
    if (t < 20) {
        float a = b1[t];
        for (int k = 0; k < DH; k++) a += gv[k] * W1[k * 20 + t];
        mid[t] = fmaxf(a, 0.f);
    }
    __syncthreads();
    if (t < 10) {
        float a = b2[t];
        for (int k = 0; k < 20; k++) a += mid[k] * W2[k * 10 + t];
        o[t] = a;
    }
    __syncthreads();
    if (t == 0) {
        float m = -1e30f;
        for (int j = 0; j < 10; j++) m = fmaxf(m, o[j]);
        float ssum = 0.f;
        for (int j = 0; j < 10; j++) ssum += expf(o[j] - m);
        float l = logf(ssum);
        for (int j = 0; j < 10; j++) out[g * 10 + j] = o[j] - m - l;
    }
}

extern "C" void kernel_launch(void* const* d_in, const int* in_sizes, int n_in,
                              void* d_out, int out_size, void* d_ws, size_t ws_size,
                              hipStream_t stream) {
    const float* x    = (const float*)d_in[0];
    const int*   ei   = (const int*)d_in[1];
    const int*   batch= (const int*)d_in[2];
    const float* W1   = (const float*)d_in[3];
    const float* b1   = (const float*)d_in[4];
    const float* W2   = (const float*)d_in[5];
    const float* b2   = (const float*)d_in[6];
    const float* fc1W = (const float*)d_in[7];
    const float* fc1b = (const float*)d_in[8];
    const float* fc2W = (const float*)d_in[9];
    const float* fc2b = (const float*)d_in[10];
    float* out = (float*)d_out;

    int N = in_sizes[0] / DH;     // 100000
    int E = in_sizes[1] / 2;      // 1600000
    int G = out_size / 10;        // 64

    char* p = (char*)d_ws;
    auto alloc = [&](size_t bytes) {
        char* r = p;
        p += (bytes + 255) & ~(size_t)255;
        return r;
    };
    unsigned char*  t8 = (unsigned char*)alloc((size_t)N * DH);      // fp8 hidden table
    unsigned short* a1 = (unsigned short*)alloc((size_t)N * DH * 2); // bf16 act (both layers)
    int*   csr  = (int*)alloc((size_t)E * 4);
    int*   off  = (int*)alloc((size_t)(N + 1) * 4);
    float* dinv = (float*)alloc((size_t)N * 4);
    int nbuck = (N + 511) >> 9;   // 196
    unsigned int* pairs = (unsigned int*)alloc((size_t)nbuck * BCAP * 4);
    unsigned short* Wt1 = (unsigned short*)alloc(DH * DH * 2);
    unsigned short* Wt2 = (unsigned short*)alloc(DH * DH * 2);
    float* Gsum = (float*)alloc((size_t)G * DH * 4);
    int*   bcur = (int*)alloc(256 * 16 * 4);
    int*   cnts = (int*)alloc((size_t)G * 4);

    const int* row = ei;       // message source
    const int* col = ei + E;   // aggregation target

    (void)hipMemsetAsync(Gsum, 0, (size_t)G * DH * 4 + 256 * 16 * 4, stream);

    const int chunk = 8192;
    int ablocks = (E + chunk - 1) / chunk;  // 196
    k_bucket<<<ablocks, 256, 0, stream>>>(row, col, E, nbuck, chunk, pairs, bcur);
    k_build<<<nbuck, 256, 0, stream>>>(pairs, bcur, nbuck, N, off, dinv, csr);
    k_prepW<<<128, 256, 0, stream>>>(W1, W2, Wt1, Wt2);

    int gblocks = (N + 63) / 64;
    int mblocks = (N + 15) / 16;  // 6250
    // layer 1
    k_gemm_mfma<<<gblocks, 256, 0, stream>>>(x, 0, Wt1, dinv, t8, N);
    k_agg<<<mblocks, 256, 0, stream>>>(t8, a1, dinv, off, csr, b1, 1, N);
    // layer 2
    k_gemm_mfma<<<gblocks, 256, 0, stream>>>(a1, 1, Wt2, dinv, t8, N);
    k_agg<<<mblocks, 256, 0, stream>>>(t8, a1, dinv, off, csr, b2, 0, N);

    dim3 pg(G, 32);
    k_pool<<<pg, 256, 0, stream>>>((const unsigned int*)a1, batch, Gsum, cnts, N);
    k_head<<<G, 64, 0, stream>>>(Gsum, cnts, fc1W, fc1b, fc2W, fc2b, out);
}